// Round 8
// baseline (505.610 us; speedup 1.0000x reference)
//
#include <hip/hip_runtime.h>
#include <hip/hip_bf16.h>
#include <cstdint>
#include <cstddef>

typedef unsigned short u16;
typedef __bf16 bf16x8 __attribute__((ext_vector_type(8)));
typedef float f32x4 __attribute__((ext_vector_type(4)));

#define B_ROWS 4096
#define N_HIDDEN 2048
#define DT_RANK 128

static __device__ __forceinline__ u16 f2bf(float f) {
  unsigned u = __float_as_uint(f);
  u += 0x7FFFu + ((u >> 16) & 1u);   // RTNE
  return (u16)(u >> 16);
}
static __device__ __forceinline__ float bf2f(u16 b) {
  return __uint_as_float(((unsigned)b) << 16);
}
static __device__ __forceinline__ float siluf(float v) {
  return v / (1.0f + __expf(-v));
}
static __device__ __forceinline__ float softplusf(float v) {
  return v > 15.0f ? v : log1pf(__expf(v));
}
static __device__ __forceinline__ void async16(void* lds, const void* g) {
  __builtin_amdgcn_global_load_lds((const __attribute__((address_space(1))) void*)g,
                                   (__attribute__((address_space(3))) void*)lds, 16, 0, 0);
}

// ---------------- merged f32 -> bf16 convert (all tensors, one launch) ----------------
struct CvtJobs {
  const float* src[8];
  u16* dst[8];
  int rl4[8];      // row length in float4 units
  int dstride[8];  // dst row stride in u16 units
  int cum[9];      // cumulative row counts
};
__global__ __launch_bounds__(256)
void cvt_all_kernel(CvtJobs J) {
  int b = blockIdx.x;
  int job = 0;
#pragma unroll
  for (int k = 1; k < 8; ++k) if (b >= J.cum[k]) job = k;
  const int row = b - J.cum[job];
  const int rl4 = J.rl4[job];
  const float4* s = (const float4*)(J.src[job] + (size_t)row * (rl4 * 4));
  ushort4* d = (ushort4*)(J.dst[job] + (size_t)row * J.dstride[job]);
  for (int c = threadIdx.x; c < rl4; c += blockDim.x) {
    float4 f = s[c];
    ushort4 o;
    o.x = f2bf(f.x); o.y = f2bf(f.y); o.z = f2bf(f.z); o.w = f2bf(f.w);
    d[c] = o;
  }
}

// ================= 256x256 GEMM: read-ahead-1 phases, 1 barrier/phase =================
// Wave grid 2Mx4N; wave (wr,wc) output quadrants Qab = rows a*128+wr*64.., cols b*128+wc*32..
// Per K-tile j (buf c), phases consume: q0=Q00(fa,fb0) q1=Q01(fa,fb1) q2=Q10(fah,fb0) q3=Q11(fah,fb1).
// READ-AHEAD: phase p issues the reads consumed at p+1 (frag arrays refilled exactly when dead):
//   R(q0)=fb1<-B1(j,cur)  R(q1)=fah<-A1(j,cur)  R(q2)=fa<-A0(j+1,nxt)  R(q3)=fb0<-B0(j+1,nxt)
// STAGES (1 half/phase): S(q0)=B0(j+1,nxt) S(q1)=B1(j+1,nxt) S(q2)=A1(j+1,nxt) S(q3)=A0(j+2,cur)
// Each R(p) reads data staged exactly at p-3; the uniform vmcnt(4) at end(p-1) retires S(p-3)
// (outstanding after S(p-1): S(p-3),S(p-2),S(p-1)=6 loads -> wait to 4 retires oldest), and the
// barrier at end(p-1) makes that landing cross-wave-visible before R(p). WAR: slot overwritten by
// S(p) had its last ds_read at (p-3)-start, retired by the compiler's lgkm wait before that read's
// consuming MFMA at p-2, >=2 barriers earlier. lgkm waits: compiler-counted (plain-C ds reads);
// vmcnt + memory-clobbers are manual (compiler can't see global_load_lds -> ds_read dependency).
// Tail j>=NT-2: vmcnt(0) every phase end; dead reads/stages skipped.
// Phase: { reads(p+1); stage; setprio1 MFMA setprio0; vmcnt; barrier }  -- ONE barrier/phase.
// Swizzle: 16B-chunk ^= (row&7) on global source + ds_read address (LDS dest linear).
template <int NN, int KK, int LDA, int LDB, int EPI>
__global__ __launch_bounds__(512, 1)
void gemm8(const u16* __restrict__ A, const u16* __restrict__ Bw,
           float* __restrict__ outf, u16* __restrict__ outb, long long zstride)
{
  extern __shared__ u16 lds[];
  u16* ldsA = lds;            // 4 slots (buf*2+half) * 8192 u16 = 64 KiB
  u16* ldsB = lds + 32768;    // 64 KiB
  constexpr int NT = KK / 64;
  static_assert(NT >= 3, "schedule assumes NT >= 3");

  const int t = threadIdx.x;
  const int lane = t & 63, w = t >> 6;
  const int wr = w >> 2, wc = w & 3;      // wave grid 2M x 4N
  const int r = lane & 15;
  const int q4 = lane >> 4;               // 0..3 (k-quad)

  const int gx = gridDim.x;
  const int nwg = gx * gridDim.y;
  const int bid = blockIdx.y * gx + blockIdx.x;
  const int cpx = nwg >> 3;
  const int swz = (bid & 7) * cpx + (bid >> 3);   // bijective XCD swizzle (nwg%8==0)
  const int n0 = (swz % gx) * 256;
  const int m0 = (swz / gx) * 256;
  const int koff = blockIdx.z * KK;

  f32x4 acc[2][2][4][2] = {};   // [a][b][fi][g]

  auto stA = [&](int buf, int half, int k0) {
#pragma unroll
    for (int i = 0; i < 2; ++i) {
      const int ii = w * 2 + i;
      const int c = ii * 64 + lane;          // 16B-chunk index in half-tile
      const int row = c >> 3;
      const int ch = (c & 7) ^ (row & 7);    // inverse-swizzled global chunk
      async16(ldsA + (buf * 2 + half) * 8192 + ii * 512,
              A + (size_t)(m0 + half * 128 + row) * LDA + (koff + k0 + ch * 8));
    }
  };
  auto stB = [&](int buf, int half, int k0) {
#pragma unroll
    for (int i = 0; i < 2; ++i) {
      const int ii = w * 2 + i;
      const int c = ii * 64 + lane;
      const int row = c >> 3;
      const int ch = (c & 7) ^ (row & 7);
      async16(ldsB + (buf * 2 + half) * 8192 + ii * 512,
              Bw + (size_t)(n0 + half * 128 + row) * LDB + (koff + k0 + ch * 8));
    }
  };

  // fragment reads (16x16x32): lr = local row in half (0..127), kki = K32-slice 0..1
  auto ldA = [&](int buf, int half, int lr, int kki) -> bf16x8 {
    const int tt = kki * 4 + q4;
    return *(const bf16x8*)(ldsA + (size_t)((buf * 2 + half) * 8192 + lr * 64 + ((tt ^ (lr & 7)) << 3)));
  };
  auto ldB = [&](int buf, int half, int lr, int kki) -> bf16x8 {
    const int tt = kki * 4 + q4;
    return *(const bf16x8*)(ldsB + (size_t)((buf * 2 + half) * 8192 + lr * 64 + ((tt ^ (lr & 7)) << 3)));
  };

  bf16x8 fa[8], fah[8], fb0[4], fb1[4];

  // ---- prologue: stage A0(0),B0(0),B1(0),A1(0),A0(1); vmcnt(4) lands first 3;
  //      barrier; pre-issue fa<-A0(0), fb0<-B0(0).
  stA(0, 0, 0); stB(0, 0, 0); stB(0, 1, 0); stA(0, 1, 0);
  stA(1, 0, 64);
  asm volatile("s_waitcnt vmcnt(4)" ::: "memory");
  __builtin_amdgcn_s_barrier();
  asm volatile("" ::: "memory");
#pragma unroll
  for (int fi = 0; fi < 4; ++fi)
#pragma unroll
    for (int ks = 0; ks < 2; ++ks)
      fa[fi * 2 + ks] = ldA(0, 0, wr * 64 + fi * 16 + r, ks);
#pragma unroll
  for (int g = 0; g < 2; ++g)
#pragma unroll
    for (int ks = 0; ks < 2; ++ks)
      fb0[g * 2 + ks] = ldB(0, 0, wc * 32 + g * 16 + r, ks);

  int cur = 0;
  for (int j = 0; j < NT; ++j) {
    const int nxt = cur ^ 1;
    const bool t1 = (j + 1 >= NT);
    const bool t2 = (j + 2 >= NT);
    const bool deep = (j < NT - 2);

    // ======== q0: read fb1<-B1(j); stage B0(j+1); MFMA Q00; vmcnt; barrier
#pragma unroll
    for (int g = 0; g < 2; ++g)
#pragma unroll
      for (int ks = 0; ks < 2; ++ks)
        fb1[g * 2 + ks] = ldB(cur, 1, wc * 32 + g * 16 + r, ks);
    if (!t1) stB(nxt, 0, (j + 1) * 64);
    __builtin_amdgcn_s_setprio(1);
#pragma unroll
    for (int fi = 0; fi < 4; ++fi)
#pragma unroll
      for (int g = 0; g < 2; ++g) {
        acc[0][0][fi][g] = __builtin_amdgcn_mfma_f32_16x16x32_bf16(fa[fi * 2 + 0], fb0[g * 2 + 0], acc[0][0][fi][g], 0, 0, 0);
        acc[0][0][fi][g] = __builtin_amdgcn_mfma_f32_16x16x32_bf16(fa[fi * 2 + 1], fb0[g * 2 + 1], acc[0][0][fi][g], 0, 0, 0);
      }
    __builtin_amdgcn_s_setprio(0);
    if (deep) { asm volatile("s_waitcnt vmcnt(4)" ::: "memory"); }
    else      { asm volatile("s_waitcnt vmcnt(0)" ::: "memory"); }
    __builtin_amdgcn_s_barrier();
    asm volatile("" ::: "memory");

    // ======== q1: read fah<-A1(j); stage B1(j+1); MFMA Q01; vmcnt; barrier
#pragma unroll
    for (int fi = 0; fi < 4; ++fi)
#pragma unroll
      for (int ks = 0; ks < 2; ++ks)
        fah[fi * 2 + ks] = ldA(cur, 1, wr * 64 + fi * 16 + r, ks);
    if (!t1) stB(nxt, 1, (j + 1) * 64);
    __builtin_amdgcn_s_setprio(1);
#pragma unroll
    for (int fi = 0; fi < 4; ++fi)
#pragma unroll
      for (int g = 0; g < 2; ++g) {
        acc[0][1][fi][g] = __builtin_amdgcn_mfma_f32_16x16x32_bf16(fa[fi * 2 + 0], fb1[g * 2 + 0], acc[0][1][fi][g], 0, 0, 0);
        acc[0][1][fi][g] = __builtin_amdgcn_mfma_f32_16x16x32_bf16(fa[fi * 2 + 1], fb1[g * 2 + 1], acc[0][1][fi][g], 0, 0, 0);
      }
    __builtin_amdgcn_s_setprio(0);
    if (deep) { asm volatile("s_waitcnt vmcnt(4)" ::: "memory"); }
    else      { asm volatile("s_waitcnt vmcnt(0)" ::: "memory"); }
    __builtin_amdgcn_s_barrier();
    asm volatile("" ::: "memory");

    // ======== q2: read fa<-A0(j+1,nxt); stage A1(j+1); MFMA Q10; vmcnt; barrier
    if (!t1) {
#pragma unroll
      for (int fi = 0; fi < 4; ++fi)
#pragma unroll
        for (int ks = 0; ks < 2; ++ks)
          fa[fi * 2 + ks] = ldA(nxt, 0, wr * 64 + fi * 16 + r, ks);
      stA(nxt, 1, (j + 1) * 64);
    }
    __builtin_amdgcn_s_setprio(1);
#pragma unroll
    for (int fi = 0; fi < 4; ++fi)
#pragma unroll
      for (int g = 0; g < 2; ++g) {
        acc[1][0][fi][g] = __builtin_amdgcn_mfma_f32_16x16x32_bf16(fah[fi * 2 + 0], fb0[g * 2 + 0], acc[1][0][fi][g], 0, 0, 0);
        acc[1][0][fi][g] = __builtin_amdgcn_mfma_f32_16x16x32_bf16(fah[fi * 2 + 1], fb0[g * 2 + 1], acc[1][0][fi][g], 0, 0, 0);
      }
    __builtin_amdgcn_s_setprio(0);
    if (deep) { asm volatile("s_waitcnt vmcnt(4)" ::: "memory"); }
    else      { asm volatile("s_waitcnt vmcnt(0)" ::: "memory"); }
    __builtin_amdgcn_s_barrier();
    asm volatile("" ::: "memory");

    // ======== q3: read fb0<-B0(j+1,nxt); stage A0(j+2,cur); MFMA Q11; vmcnt; barrier
    if (!t1) {
#pragma unroll
      for (int g = 0; g < 2; ++g)
#pragma unroll
        for (int ks = 0; ks < 2; ++ks)
          fb0[g * 2 + ks] = ldB(nxt, 0, wc * 32 + g * 16 + r, ks);
    }
    if (!t2) stA(cur, 0, (j + 2) * 64);
    __builtin_amdgcn_s_setprio(1);
#pragma unroll
    for (int fi = 0; fi < 4; ++fi)
#pragma unroll
      for (int g = 0; g < 2; ++g) {
        acc[1][1][fi][g] = __builtin_amdgcn_mfma_f32_16x16x32_bf16(fah[fi * 2 + 0], fb1[g * 2 + 0], acc[1][1][fi][g], 0, 0, 0);
        acc[1][1][fi][g] = __builtin_amdgcn_mfma_f32_16x16x32_bf16(fah[fi * 2 + 1], fb1[g * 2 + 1], acc[1][1][fi][g], 0, 0, 0);
      }
    __builtin_amdgcn_s_setprio(0);
    if (deep) { asm volatile("s_waitcnt vmcnt(4)" ::: "memory"); }
    else      { asm volatile("s_waitcnt vmcnt(0)" ::: "memory"); }
    __builtin_amdgcn_s_barrier();
    asm volatile("" ::: "memory");
    cur = nxt;
  }

  // ---- epilogue: C/D 16x16 layout col=lane&15, row=(lane>>4)*4+reg
  float* of = outf ? (outf + (size_t)blockIdx.z * zstride) : nullptr;
#pragma unroll
  for (int a = 0; a < 2; ++a)
#pragma unroll
    for (int b = 0; b < 2; ++b)
#pragma unroll
      for (int fi = 0; fi < 4; ++fi)
#pragma unroll
        for (int g = 0; g < 2; ++g)
#pragma unroll
          for (int tt = 0; tt < 4; ++tt) {
            const int grow = m0 + a * 128 + wr * 64 + fi * 16 + q4 * 4 + tt;
            const int gcol = n0 + b * 128 + wc * 32 + g * 16 + r;
            const float v = acc[a][b][fi][g][tt];
            if constexpr (EPI == 0) {
              outb[(size_t)grow * NN + gcol] = f2bf(siluf(v));
            } else {
              of[(size_t)grow * NN + gcol] = v;
            }
          }
}

// ---------------- 128x128 2-phase GEMM (kept for the K=128 y-GEMM) ----------------
template <int NN, int KK, int LDA, int EPI>
__global__ __launch_bounds__(256)
void gemm_bt(const u16* __restrict__ A, const u16* __restrict__ Bw,
             float* __restrict__ outf, u16* __restrict__ outb,
             const float* __restrict__ aux1, const float* __restrict__ aux2,
             const float* __restrict__ aux3,
             const u16* __restrict__ xaux, const u16* __restrict__ saux)
{
  constexpr int BM = 128, BK = 64;
  __shared__ alignas(16) u16 As[2][BM * BK];
  __shared__ alignas(16) u16 Bs[2][BM * BK];
  const int t = threadIdx.x;
  const int lane = t & 63, w = t >> 6;
  const int m0 = blockIdx.y * BM, n0 = blockIdx.x * BM;
  const int mw = (w >> 1) * 64, nw = (w & 1) * 64;
  const int r = lane & 15;
  const int kq = (lane >> 4) * 8;

  f32x4 acc[4][4] = {};

  auto stage = [&](int buf, int k0) {
#pragma unroll
    for (int i = 0; i < 4; ++i) {
      const int slot0 = (w * 4 + i) * 64;
      const int s = slot0 + lane;
      const int row = s >> 3, cs = (s & 7) * 8;
      async16(&As[buf][slot0 * 8], A + (size_t)(m0 + row) * LDA + k0 + cs);
      async16(&Bs[buf][slot0 * 8], Bw + (size_t)(n0 + row) * KK + k0 + cs);
    }
  };

  stage(0, 0);
  asm volatile("s_waitcnt vmcnt(0)" ::: "memory");
  __syncthreads();
  int cur = 0;

  for (int k0 = 0; k0 < KK; k0 += BK) {
    if (k0 + BK < KK) stage(cur ^ 1, k0 + BK);
#pragma unroll
    for (int kk = 0; kk < BK; kk += 32) {
      bf16x8 af[4], bb[4];
#pragma unroll
      for (int f = 0; f < 4; ++f)
        af[f] = *(const bf16x8*)(&As[cur][(mw + f * 16 + r) * BK + kk + kq]);
#pragma unroll
      for (int f = 0; f < 4; ++f)
        bb[f] = *(const bf16x8*)(&Bs[cur][(nw + f * 16 + r) * BK + kk + kq]);
#pragma unroll
      for (int fm = 0; fm < 4; ++fm)
#pragma unroll
        for (int fn = 0; fn < 4; ++fn)
          acc[fm][fn] = __builtin_amdgcn_mfma_f32_16x16x32_bf16(af[fm], bb[fn], acc[fm][fn], 0, 0, 0);
    }
    asm volatile("s_waitcnt vmcnt(0)" ::: "memory");
    __syncthreads();
    cur ^= 1;
  }

  const int rr = (lane >> 4) * 4;
  const int cc = lane & 15;
#pragma unroll
  for (int fm = 0; fm < 4; ++fm) {
#pragma unroll
    for (int fn = 0; fn < 4; ++fn) {
#pragma unroll
      for (int tt = 0; tt < 4; ++tt) {
        const int grow = m0 + mw + fm * 16 + rr + tt;
        const int gcol = n0 + nw + fn * 16 + cc;
        float v = acc[fm][fn][tt];
        if constexpr (EPI == 2) {
          float dt = softplusf(v + aux1[gcol]);
          float xv = bf2f(xaux[(size_t)grow * NN + gcol]);
          float sv = bf2f(saux[(size_t)grow * NN + gcol]);
          float yv = xv * (dt * aux2[grow] + aux3[gcol]) * sv;
          outb[(size_t)grow * NN + gcol] = f2bf(yv);
        } else {
          outf[(size_t)grow * NN + gcol] = v;
        }
      }
    }
  }
}

// ---------------- skinny GEMM: part[kz] = xbr @ Wxp^T over K-chunk ----------------
__global__ __launch_bounds__(256)
void gemm_xproj(const u16* __restrict__ A, const u16* __restrict__ Bw,
                float* __restrict__ part)
{
  constexpr int BK = 64;
  __shared__ alignas(16) u16 As[64 * BK];
  __shared__ alignas(16) u16 Bs[160 * BK];
  const int t = threadIdx.x, lane = t & 63, w = t >> 6;
  const int m0 = blockIdx.x * 64;
  const int kz = blockIdx.y;
  const int r = lane & 15, kq = (lane >> 4) * 8;
  f32x4 acc[10] = {};
  for (int kt = 0; kt < 1024; kt += BK) {
    const int k0 = kz * 1024 + kt;
#pragma unroll
    for (int i = 0; i < 2; ++i) {
      const int slot0 = (w * 2 + i) * 64;
      const int s = slot0 + lane;
      async16(As + slot0 * 8, A + (size_t)(m0 + (s >> 3)) * 4096 + k0 + (s & 7) * 8);
    }
#pragma unroll
    for (int i = 0; i < 5; ++i) {
      const int slot0 = (w * 5 + i) * 64;
      const int s = slot0 + lane;
      async16(Bs + slot0 * 8, Bw + (size_t)(s >> 3) * 4096 + k0 + (s & 7) * 8);
    }
    asm volatile("s_waitcnt vmcnt(0)" ::: "memory");
    __syncthreads();
#pragma unroll
    for (int kk = 0; kk < BK; kk += 32) {
      bf16x8 af = *(const bf16x8*)(As + (w * 16 + r) * BK + kk + kq);
#pragma unroll
      for (int fn = 0; fn < 10; ++fn) {
        bf16x8 bb = *(const bf16x8*)(Bs + (fn * 16 + r) * BK + kk + kq);
        acc[fn] = __builtin_amdgcn_mfma_f32_16x16x32_bf16(af, bb, acc[fn], 0, 0, 0);
      }
    }
    __syncthreads();
  }
  float* o = part + (size_t)kz * B_ROWS * 160;
  const int rr = (lane >> 4) * 4, cc = lane & 15;
#pragma unroll
  for (int fn = 0; fn < 10; ++fn)
#pragma unroll
    for (int tt = 0; tt < 4; ++tt)
      o[(size_t)(m0 + w * 16 + rr + tt) * 160 + fn * 16 + cc] = acc[fn][tt];
}

// ---------------- reduce split-K partials -> dt_lo (bf16) + bc ----------------
__global__ __launch_bounds__(192)
void xdbl_reduce(const float* __restrict__ part, u16* __restrict__ dtlo,
                 float* __restrict__ bc)
{
  const int row = blockIdx.x, t = threadIdx.x;
  __shared__ float cvals[32];
  float v = 0.0f;
  if (t < 160) {
    const float* p = part + (size_t)row * 160 + t;
#pragma unroll
    for (int z = 0; z < 4; ++z) v += p[(size_t)z * B_ROWS * 160];
  }
  if (t < DT_RANK) dtlo[(size_t)row * DT_RANK + t] = f2bf(v);
  if (t >= DT_RANK && t < 160) cvals[t - DT_RANK] = v;
  __syncthreads();
  if (t == 0) {
    float s = 0.0f;
#pragma unroll
    for (int j = 0; j < 16; ++j) s += cvals[j] * cvals[j + 16];
    bc[row] = s;
  }
}

// ---------------- row LayerNorm over (p0 + p1 + h) ----------------
__global__ __launch_bounds__(256)
void ln_kernel(const float* __restrict__ p0, const float* __restrict__ p1,
               const float* __restrict__ hh, const float* __restrict__ gamma,
               const float* __restrict__ beta, float* __restrict__ out)
{
  const int row = blockIdx.x, t = threadIdx.x;
  __shared__ float red[4];
  const float4* x0 = (const float4*)(p0 + (size_t)row * N_HIDDEN);
  const float4* x1 = (const float4*)(p1 + (size_t)row * N_HIDDEN);
  const float4* xh = (const float4*)(hh + (size_t)row * N_HIDDEN);
  float4 a, b;
  {
    float4 u = x0[t], v = x1[t], w = xh[t];
    a.x = u.x + v.x + w.x; a.y = u.y + v.y + w.y; a.z = u.z + v.z + w.z; a.w = u.w + v.w + w.w;
    u = x0[t + 256]; v = x1[t + 256]; w = xh[t + 256];
    b.x = u.x + v.x + w.x; b.y = u.y + v.y + w.y; b.z = u.z + v.z + w.z; b.w = u.w + v.w + w.w;
  }
  float s = ((a.x + a.y) + (a.z + a.w)) + ((b.x + b.y) + (b.z + b.w));
#pragma unroll
  for (int m = 32; m; m >>= 1) s += __shfl_xor(s, m);
  if ((t & 63) == 0) red[t >> 6] = s;
  __syncthreads();
  s = (red[0] + red[1]) + (red[2] + red[3]);
  const float mu = s * (1.0f / N_HIDDEN);
  float dx0 = a.x - mu, dx1 = a.y - mu, dx2 = a.z - mu, dx3 = a.w - mu;
  float dy0 = b.x - mu, dy1 = b.y - mu, dy2 = b.z - mu, dy3 = b.w - mu;
  float q = ((dx0 * dx0 + dx1 * dx1) + (dx2 * dx2 + dx3 * dx3)) +
            ((dy0 * dy0 + dy1 * dy1) + (dy2 * dy2 + dy3 * dy3));
  __syncthreads();
#pragma unroll
  for (int m = 32; m; m >>= 1) q += __shfl_xor(q, m);
  if ((t & 63) == 0) red[t >> 6] = q;
  __syncthreads();
  q = (red[0] + red[1]) + (red[2] + red[3]);
  const float inv = rsqrtf(q * (1.0f / N_HIDDEN) + 1e-5f);
  const float4 ga = ((const float4*)gamma)[t], gb = ((const float4*)gamma)[t + 256];
  const float4 ba = ((const float4*)beta)[t], bbv = ((const float4*)beta)[t + 256];
  float4 o0, o1;
  o0.x = dx0 * inv * ga.x + ba.x;
  o0.y = dx1 * inv * ga.y + ba.y;
  o0.z = dx2 * inv * ga.z + ba.z;
  o0.w = dx3 * inv * ga.w + ba.w;
  o1.x = dy0 * inv * gb.x + bbv.x;
  o1.y = dy1 * inv * gb.y + bbv.y;
  o1.z = dy2 * inv * gb.z + bbv.z;
  o1.w = dy3 * inv * gb.w + bbv.w;
  float4* o4 = (float4*)(out + (size_t)row * N_HIDDEN);
  o4[t] = o0;
  o4[t + 256] = o1;
}

// ---------------- launch ----------------
extern "C" void kernel_launch(void* const* d_in, const int* in_sizes, int n_in,
                              void* d_out, int out_size, void* d_ws, size_t ws_size,
                              hipStream_t stream) {
  const float* x     = (const float*)d_in[0];
  const float* h     = (const float*)d_in[1];
  const float* W_in  = (const float*)d_in[2];
  const float* W_st  = (const float*)d_in[3];
  const float* W_xp  = (const float*)d_in[4];
  const float* W_dt  = (const float*)d_in[5];
  const float* b_dt  = (const float*)d_in[6];
  const float* Dv    = (const float*)d_in[8];
  const float* W_out = (const float*)d_in[9];
  const float* gamma = (const float*)d_in[10];
  const float* beta  = (const float*)d_in[11];
  float* out = (float*)d_out;
  (void)in_sizes; (void)n_in; (void)out_size; (void)ws_size;

  char* ws = (char*)d_ws;
  size_t o = 0;
  auto alloc = [&](size_t bytes) { char* p = ws + o; o += bytes; return p; };
  u16* Acat    = (u16*)alloc((size_t)4096 * 3072 * 2);  // [x | h]   (region reused for y)
  u16* Wcat    = (u16*)alloc((size_t)4096 * 3072 * 2);  // [W_in_lo | W_st]
  u16* Wz_bf   = (u16*)alloc((size_t)4096 * 1024 * 2);
  u16* Wxp_bf  = (u16*)alloc((size_t)160 * 4096 * 2);
  u16* Wdt_bf  = (u16*)alloc((size_t)4096 * 128 * 2);
  u16* Wout_bf = (u16*)alloc((size_t)2048 * 4096 * 2);
  u16* xbr_bf  = (u16*)alloc((size_t)4096 * 4096 * 2);  // reused for p0 (f32)
  u16* sz_bf   = (u16*)alloc((size_t)4096 * 4096 * 2);  // reused for p1 (f32)
  float* part  = (float*)alloc((size_t)4 * 4096 * 160 * 4);
  u16* dtlo_bf = (u16*)alloc((size_t)4096 * 128 * 2);
  float* bc    = (float*)alloc((size_t)4096 * 4);
  // overlays (lifetimes are disjoint):
  u16* y_bf = (u16*)Acat;                  // Acat+Wcat dead by then
  float* p0 = (float*)xbr_bf;              // W_out split-K partials, contiguous
  float* p1 = p0 + (size_t)4096 * 2048;

  // ---- single merged convert launch (8 jobs)
  CvtJobs J;
  J.src[0] = x;                           J.dst[0] = Acat;        J.rl4[0] = 256;  J.dstride[0] = 3072;
  J.src[1] = h;                           J.dst[1] = Acat + 1024; J.rl4[1] = 512;  J.dstride[1] = 3072;
  J.src[2] = W_in;                        J.dst[2] = Wcat;        J.rl4[2] = 256;  J.dstride[2] = 3072;
  J.src[3] = W_st;                        J.dst[3] = Wcat + 1024; J.rl4[3] = 512;  J.dstride[3] = 3072;
  J.src[4] = W_in + (size_t)4096 * 1024;  J.dst[4] = Wz_bf;       J.rl4[4] = 256;  J.dstride[4] = 1024;
  J.src[5] = W_xp;                        J.dst[5] = Wxp_bf;      J.rl4[5] = 1024; J.dstride[5] = 4096;
  J.src[6] = W_dt;                        J.dst[6] = Wdt_bf;      J.rl4[6] = 32;   J.dstride[6] = 128;
  J.src[7] = W_out;                       J.dst[7] = Wout_bf;     J.rl4[7] = 1024; J.dstride[7] = 4096;
  const int rows[8] = {4096, 4096, 4096, 4096, 4096, 160, 4096, 2048};
  J.cum[0] = 0;
  for (int k = 0; k < 8; ++k) J.cum[k + 1] = J.cum[k] + rows[k];
  cvt_all_kernel<<<J.cum[8], 256, 0, stream>>>(J);

  // x_br = silu([x|h] @ [W_in_lo|W_st]^T)   M=4096,N=4096,K=3072
  gemm8<4096, 3072, 3072, 3072, 0><<<dim3(16, 16, 1), 512, 131072, stream>>>(
      Acat, Wcat, nullptr, xbr_bf, 0);
  // sz = silu(x @ W_in_hi^T)                M=4096,N=4096,K=1024
  gemm8<4096, 1024, 3072, 1024, 0><<<dim3(16, 16, 1), 512, 131072, stream>>>(
      Acat, Wz_bf, nullptr, sz_bf, 0);
  // x_dbl split-K partials + reduce -> dt_lo, bc
  gemm_xproj<<<dim3(64, 4), 256, 0, stream>>>(xbr_bf, Wxp_bf, part);
  xdbl_reduce<<<4096, 192, 0, stream>>>(part, dtlo_bf, bc);
  // y = x_br*(softplus(dt_pre+b_dt)*bc + D)*silu(z)   M=4096,N=4096,K=128
  gemm_bt<4096, 128, 128, 2><<<dim3(32, 32), 256, 0, stream>>>(
      dtlo_bf, Wdt_bf, nullptr, y_bf, b_dt, bc, Dv, xbr_bf, sz_bf);
  // h_new partials: y @ W_out^T, split-K=2  M=4096,N=2048,K=2x2048
  gemm8<2048, 2048, 4096, 4096, 1><<<dim3(8, 16, 2), 512, 131072, stream>>>(
      y_bf, Wout_bf, p0, nullptr, (long long)4096 * 2048);
  // LayerNorm(p0 + p1 + h) -> out
  ln_kernel<<<4096, 256, 0, stream>>>(p0, p1, h, gamma, beta, out);
}

// Round 9
// 358.382 us; speedup vs baseline: 1.4108x; 1.4108x over previous
//
#include <hip/hip_runtime.h>
#include <hip/hip_bf16.h>
#include <cstdint>
#include <cstddef>

typedef unsigned short u16;
typedef __bf16 bf16x8 __attribute__((ext_vector_type(8)));
typedef float f32x4 __attribute__((ext_vector_type(4)));

#define B_ROWS 4096
#define N_HIDDEN 2048
#define DT_RANK 128

static __device__ __forceinline__ u16 f2bf(float f) {
  unsigned u = __float_as_uint(f);
  u += 0x7FFFu + ((u >> 16) & 1u);   // RTNE
  return (u16)(u >> 16);
}
static __device__ __forceinline__ float bf2f(u16 b) {
  return __uint_as_float(((unsigned)b) << 16);
}
static __device__ __forceinline__ float siluf(float v) {
  return v / (1.0f + __expf(-v));
}
static __device__ __forceinline__ float softplusf(float v) {
  return v > 15.0f ? v : log1pf(__expf(v));
}
static __device__ __forceinline__ void async16(void* lds, const void* g) {
  __builtin_amdgcn_global_load_lds((const __attribute__((address_space(1))) void*)g,
                                   (__attribute__((address_space(3))) void*)lds, 16, 0, 0);
}

// ---------------- merged f32 -> bf16 convert (all tensors, one launch) ----------------
struct CvtJobs {
  const float* src[8];
  u16* dst[8];
  int rl4[8];      // row length in float4 units
  int dstride[8];  // dst row stride in u16 units
  int cum[9];      // cumulative row counts
};
__global__ __launch_bounds__(256)
void cvt_all_kernel(CvtJobs J) {
  int b = blockIdx.x;
  int job = 0;
#pragma unroll
  for (int k = 1; k < 8; ++k) if (b >= J.cum[k]) job = k;
  const int row = b - J.cum[job];
  const int rl4 = J.rl4[job];
  const float4* s = (const float4*)(J.src[job] + (size_t)row * (rl4 * 4));
  ushort4* d = (ushort4*)(J.dst[job] + (size_t)row * J.dstride[job]);
  for (int c = threadIdx.x; c < rl4; c += blockDim.x) {
    float4 f = s[c];
    ushort4 o;
    o.x = f2bf(f.x); o.y = f2bf(f.y); o.z = f2bf(f.z); o.w = f2bf(f.w);
    d[c] = o;
  }
}

// ================= 256x256 8-phase bf16 GEMM, quadrant-phased (round-7 schedule) ======
// RECT-XCD TILING (this round's only change): consecutive blockIdx round-robin across
// XCDs (bid&7). Each XCD's cpx blocks map to an RH x RW (MxN) rectangle of 256-tiles:
// per-K-step L2 working set = (RH+RW) panels (<=384KB, L2-resident) and per-XCD panel
// traffic = (RH+RW)*panel vs (2+16) for the old linear swizzle -> -33% L3/HBM re-fetch.
// Schedule (r7, unchanged): phases q0=Q00 q1=Q01 q2=Q10 q3=Q11; reads at phase start for
// the SAME phase's MFMA; stages 1 half/phase (A0'@q0,B0'@q1,[faNxt+A1']@q2,B1... see r7);
// gates vmcnt(4) at q0,q1,q3 (tail vmcnt(0..2)); two barriers/phase.
template <int NN, int KK, int LDA, int LDB, int EPI, int GX, int GY, int RH, int RW>
__global__ __launch_bounds__(512, 1)
void gemm8(const u16* __restrict__ A, const u16* __restrict__ Bw,
           float* __restrict__ outf, u16* __restrict__ outb, long long zstride)
{
  extern __shared__ u16 lds[];
  u16* ldsA = lds;            // 4 slots (buf*2+half) * 8192 u16 = 64 KiB
  u16* ldsB = lds + 32768;    // 64 KiB
  constexpr int NT = KK / 64;
  static_assert(NT >= 2, "schedule assumes NT >= 2");
  static_assert(GX * GY == 8 * RH * RW, "rect must partition grid over 8 XCDs");
  static_assert(GX % RW == 0 && GY % RH == 0, "rect divides grid");
  constexpr int XCOLS = GX / RW;
  static_assert((GY / RH) * XCOLS == 8, "XCD grid must be 8");

  const int t = threadIdx.x;
  const int lane = t & 63, w = t >> 6;
  const int wr = w >> 2, wc = w & 3;      // wave grid 2M x 4N
  const int r = lane & 15;
  const int q4 = lane >> 4;               // 0..3 (k-quad)

  // ---- rect-XCD tile mapping (bijective; locality-only) ----
  const int bid = blockIdx.y * GX + blockIdx.x;
  const int xcd = bid & 7;
  const int i = bid >> 3;                 // 0..RH*RW-1
  const int xr = xcd / XCOLS, xc = xcd % XCOLS;
  const int m0 = (xr * RH + i / RW) * 256;
  const int n0 = (xc * RW + i % RW) * 256;
  const int koff = blockIdx.z * KK;

  f32x4 acc[2][2][4][2] = {};   // [a][b][fi][g]

  auto stA = [&](int buf, int half, int k0) {
#pragma unroll
    for (int i2 = 0; i2 < 2; ++i2) {
      const int ii = w * 2 + i2;
      const int c = ii * 64 + lane;          // 16B-chunk index in half-tile
      const int row = c >> 3;
      const int ch = (c & 7) ^ (row & 7);    // inverse-swizzled global chunk
      async16(ldsA + (buf * 2 + half) * 8192 + ii * 512,
              A + (size_t)(m0 + half * 128 + row) * LDA + (koff + k0 + ch * 8));
    }
  };
  auto stB = [&](int buf, int half, int k0) {
#pragma unroll
    for (int i2 = 0; i2 < 2; ++i2) {
      const int ii = w * 2 + i2;
      const int c = ii * 64 + lane;
      const int row = c >> 3;
      const int ch = (c & 7) ^ (row & 7);
      async16(ldsB + (buf * 2 + half) * 8192 + ii * 512,
              Bw + (size_t)(n0 + half * 128 + row) * LDB + (koff + k0 + ch * 8));
    }
  };

  // fragment reads (16x16x32): lr = local row in half (0..127), kki = K32-slice 0..1
  auto ldA = [&](int buf, int half, int lr, int kki) -> bf16x8 {
    const int tt = kki * 4 + q4;
    return *(const bf16x8*)(ldsA + (size_t)((buf * 2 + half) * 8192 + lr * 64 + ((tt ^ (lr & 7)) << 3)));
  };
  auto ldB = [&](int buf, int half, int lr, int kki) -> bf16x8 {
    const int tt = kki * 4 + q4;
    return *(const bf16x8*)(ldsB + (size_t)((buf * 2 + half) * 8192 + lr * 64 + ((tt ^ (lr & 7)) << 3)));
  };

  // ---- prologue
  stA(0, 0, 0); stB(0, 0, 0); stB(0, 1, 0); stA(0, 1, 0);
  asm volatile("s_waitcnt vmcnt(4)" ::: "memory");
  __builtin_amdgcn_s_barrier();
  asm volatile("" ::: "memory");

  int cur = 0;
  for (int j = 0; j < NT; ++j) {
    const int nxt = cur ^ 1;
    const bool lastj = (j == NT - 1);
    bf16x8 fa[8], fah[8], fb0[4], fb1[4];   // A0[fi*2+ks], A1, B0[g*2+ks], B1

    // ======== q0: read A0(8)+B0(4) ; stage A0(j+1) ; MFMA Q00 ; gate vmcnt(4)
#pragma unroll
    for (int fi = 0; fi < 4; ++fi)
#pragma unroll
      for (int ks = 0; ks < 2; ++ks)
        fa[fi * 2 + ks] = ldA(cur, 0, wr * 64 + fi * 16 + r, ks);
#pragma unroll
    for (int g = 0; g < 2; ++g)
#pragma unroll
      for (int ks = 0; ks < 2; ++ks)
        fb0[g * 2 + ks] = ldB(cur, 0, wc * 32 + g * 16 + r, ks);
    if (j + 1 < NT) stA(nxt, 0, (j + 1) * 64);
    asm volatile("" ::: "memory");
    __builtin_amdgcn_s_barrier();
    asm volatile("s_waitcnt lgkmcnt(0)" ::: "memory");
    __builtin_amdgcn_s_setprio(1);
#pragma unroll
    for (int fi = 0; fi < 4; ++fi)
#pragma unroll
      for (int g = 0; g < 2; ++g) {
        acc[0][0][fi][g] = __builtin_amdgcn_mfma_f32_16x16x32_bf16(fa[fi * 2 + 0], fb0[g * 2 + 0], acc[0][0][fi][g], 0, 0, 0);
        acc[0][0][fi][g] = __builtin_amdgcn_mfma_f32_16x16x32_bf16(fa[fi * 2 + 1], fb0[g * 2 + 1], acc[0][0][fi][g], 0, 0, 0);
      }
    __builtin_amdgcn_s_setprio(0);
    if (lastj) { asm volatile("s_waitcnt vmcnt(2)" ::: "memory"); }
    else       { asm volatile("s_waitcnt vmcnt(4)" ::: "memory"); }
    __builtin_amdgcn_s_barrier();
    asm volatile("" ::: "memory");

    // ======== q1: read B1(4) ; stage B0(j+1) ; MFMA Q01 ; gate vmcnt(4)
#pragma unroll
    for (int g = 0; g < 2; ++g)
#pragma unroll
      for (int ks = 0; ks < 2; ++ks)
        fb1[g * 2 + ks] = ldB(cur, 1, wc * 32 + g * 16 + r, ks);
    if (j + 1 < NT) stB(nxt, 0, (j + 1) * 64);
    asm volatile("" ::: "memory");
    __builtin_amdgcn_s_barrier();
    asm volatile("s_waitcnt lgkmcnt(0)" ::: "memory");
    __builtin_amdgcn_s_setprio(1);
#pragma unroll
    for (int fi = 0; fi < 4; ++fi)
#pragma unroll
      for (int g = 0; g < 2; ++g) {
        acc[0][1][fi][g] = __builtin_amdgcn_mfma_f32_16x16x32_bf16(fa[fi * 2 + 0], fb1[g * 2 + 0], acc[0][1][fi][g], 0, 0, 0);
        acc[0][1][fi][g] = __builtin_amdgcn_mfma_f32_16x16x32_bf16(fa[fi * 2 + 1], fb1[g * 2 + 1], acc[0][1][fi][g], 0, 0, 0);
      }
    __builtin_amdgcn_s_setprio(0);
    if (lastj) { asm volatile("s_waitcnt vmcnt(0)" ::: "memory"); }
    else       { asm volatile("s_waitcnt vmcnt(4)" ::: "memory"); }
    __builtin_amdgcn_s_barrier();
    asm volatile("" ::: "memory");

    // ======== q2: read A1(8) ; stage B1(j+1) ; MFMA Q10 ; no gate
#pragma unroll
    for (int fi = 0; fi < 4; ++fi)
#pragma unroll
      for (int ks = 0; ks < 2; ++ks)
        fah[fi * 2 + ks] = ldA(cur, 1, wr * 64 + fi * 16 + r, ks);
    if (j + 1 < NT) stB(nxt, 1, (j + 1) * 64);
    asm volatile("" ::: "memory");
    __builtin_amdgcn_s_barrier();
    asm volatile("s_waitcnt lgkmcnt(0)" ::: "memory");
    __builtin_amdgcn_s_setprio(1);
#pragma unroll
    for (int fi = 0; fi < 4; ++fi)
#pragma unroll
      for (int g = 0; g < 2; ++g) {
        acc[1][0][fi][g] = __builtin_amdgcn_mfma_f32_16x16x32_bf16(fah[fi * 2 + 0], fb0[g * 2 + 0], acc[1][0][fi][g], 0, 0, 0);
        acc[1][0][fi][g] = __builtin_amdgcn_mfma_f32_16x16x32_bf16(fah[fi * 2 + 1], fb0[g * 2 + 1], acc[1][0][fi][g], 0, 0, 0);
      }
    __builtin_amdgcn_s_setprio(0);
    asm volatile("" ::: "memory");
    __builtin_amdgcn_s_barrier();
    asm volatile("" ::: "memory");

    // ======== q3: no reads ; stage A1(j+1) ; MFMA Q11 ; gate vmcnt(4)
    if (j + 1 < NT) stA(nxt, 1, (j + 1) * 64);
    asm volatile("" ::: "memory");
    __builtin_amdgcn_s_barrier();
    __builtin_amdgcn_s_setprio(1);
#pragma unroll
    for (int fi = 0; fi < 4; ++fi)
#pragma unroll
      for (int g = 0; g < 2; ++g) {
        acc[1][1][fi][g] = __builtin_amdgcn_mfma_f32_16x16x32_bf16(fah[fi * 2 + 0], fb1[g * 2 + 0], acc[1][1][fi][g], 0, 0, 0);
        acc[1][1][fi][g] = __builtin_amdgcn_mfma_f32_16x16x32_bf16(fah[fi * 2 + 1], fb1[g * 2 + 1], acc[1][1][fi][g], 0, 0, 0);
      }
    __builtin_amdgcn_s_setprio(0);
    if (j + 1 < NT) { asm volatile("s_waitcnt vmcnt(4)" ::: "memory"); }
    asm volatile("" ::: "memory");
    __builtin_amdgcn_s_barrier();
    asm volatile("" ::: "memory");
    cur = nxt;
  }

  // ---- epilogue: C/D 16x16 layout col=lane&15, row=(lane>>4)*4+reg
  float* of = outf ? (outf + (size_t)blockIdx.z * zstride) : nullptr;
#pragma unroll
  for (int a = 0; a < 2; ++a)
#pragma unroll
    for (int b = 0; b < 2; ++b)
#pragma unroll
      for (int fi = 0; fi < 4; ++fi)
#pragma unroll
        for (int g = 0; g < 2; ++g)
#pragma unroll
          for (int tt = 0; tt < 4; ++tt) {
            const int grow = m0 + a * 128 + wr * 64 + fi * 16 + q4 * 4 + tt;
            const int gcol = n0 + b * 128 + wc * 32 + g * 16 + r;
            const float v = acc[a][b][fi][g][tt];
            if constexpr (EPI == 0) {
              outb[(size_t)grow * NN + gcol] = f2bf(siluf(v));
            } else {
              of[(size_t)grow * NN + gcol] = v;
            }
          }
}

// ---------------- 128x128 2-phase GEMM (kept for the K=128 y-GEMM) ----------------
template <int NN, int KK, int LDA, int EPI>
__global__ __launch_bounds__(256)
void gemm_bt(const u16* __restrict__ A, const u16* __restrict__ Bw,
             float* __restrict__ outf, u16* __restrict__ outb,
             const float* __restrict__ aux1, const float* __restrict__ aux2,
             const float* __restrict__ aux3,
             const u16* __restrict__ xaux, const u16* __restrict__ saux)
{
  constexpr int BM = 128, BK = 64;
  __shared__ alignas(16) u16 As[2][BM * BK];
  __shared__ alignas(16) u16 Bs[2][BM * BK];
  const int t = threadIdx.x;
  const int lane = t & 63, w = t >> 6;
  const int m0 = blockIdx.y * BM, n0 = blockIdx.x * BM;
  const int mw = (w >> 1) * 64, nw = (w & 1) * 64;
  const int r = lane & 15;
  const int kq = (lane >> 4) * 8;

  f32x4 acc[4][4] = {};

  auto stage = [&](int buf, int k0) {
#pragma unroll
    for (int i = 0; i < 4; ++i) {
      const int slot0 = (w * 4 + i) * 64;
      const int s = slot0 + lane;
      const int row = s >> 3, cs = (s & 7) * 8;
      async16(&As[buf][slot0 * 8], A + (size_t)(m0 + row) * LDA + k0 + cs);
      async16(&Bs[buf][slot0 * 8], Bw + (size_t)(n0 + row) * KK + k0 + cs);
    }
  };

  stage(0, 0);
  asm volatile("s_waitcnt vmcnt(0)" ::: "memory");
  __syncthreads();
  int cur = 0;

  for (int k0 = 0; k0 < KK; k0 += BK) {
    if (k0 + BK < KK) stage(cur ^ 1, k0 + BK);
#pragma unroll
    for (int kk = 0; kk < BK; kk += 32) {
      bf16x8 af[4], bb[4];
#pragma unroll
      for (int f = 0; f < 4; ++f)
        af[f] = *(const bf16x8*)(&As[cur][(mw + f * 16 + r) * BK + kk + kq]);
#pragma unroll
      for (int f = 0; f < 4; ++f)
        bb[f] = *(const bf16x8*)(&Bs[cur][(nw + f * 16 + r) * BK + kk + kq]);
#pragma unroll
      for (int fm = 0; fm < 4; ++fm)
#pragma unroll
        for (int fn = 0; fn < 4; ++fn)
          acc[fm][fn] = __builtin_amdgcn_mfma_f32_16x16x32_bf16(af[fm], bb[fn], acc[fm][fn], 0, 0, 0);
    }
    asm volatile("s_waitcnt vmcnt(0)" ::: "memory");
    __syncthreads();
    cur ^= 1;
  }

  const int rr = (lane >> 4) * 4;
  const int cc = lane & 15;
#pragma unroll
  for (int fm = 0; fm < 4; ++fm) {
#pragma unroll
    for (int fn = 0; fn < 4; ++fn) {
#pragma unroll
      for (int tt = 0; tt < 4; ++tt) {
        const int grow = m0 + mw + fm * 16 + rr + tt;
        const int gcol = n0 + nw + fn * 16 + cc;
        float v = acc[fm][fn][tt];
        if constexpr (EPI == 2) {
          float dt = softplusf(v + aux1[gcol]);
          float xv = bf2f(xaux[(size_t)grow * NN + gcol]);
          float sv = bf2f(saux[(size_t)grow * NN + gcol]);
          float yv = xv * (dt * aux2[grow] + aux3[gcol]) * sv;
          outb[(size_t)grow * NN + gcol] = f2bf(yv);
        } else {
          outf[(size_t)grow * NN + gcol] = v;
        }
      }
    }
  }
}

// ---------------- skinny GEMM: part[kz] = xbr @ Wxp^T over K-chunk ----------------
__global__ __launch_bounds__(256)
void gemm_xproj(const u16* __restrict__ A, const u16* __restrict__ Bw,
                float* __restrict__ part)
{
  constexpr int BK = 64;
  __shared__ alignas(16) u16 As[64 * BK];
  __shared__ alignas(16) u16 Bs[160 * BK];
  const int t = threadIdx.x, lane = t & 63, w = t >> 6;
  const int m0 = blockIdx.x * 64;
  const int kz = blockIdx.y;
  const int r = lane & 15, kq = (lane >> 4) * 8;
  f32x4 acc[10] = {};
  for (int kt = 0; kt < 1024; kt += BK) {
    const int k0 = kz * 1024 + kt;
#pragma unroll
    for (int i = 0; i < 2; ++i) {
      const int slot0 = (w * 2 + i) * 64;
      const int s = slot0 + lane;
      async16(As + slot0 * 8, A + (size_t)(m0 + (s >> 3)) * 4096 + k0 + (s & 7) * 8);
    }
#pragma unroll
    for (int i = 0; i < 5; ++i) {
      const int slot0 = (w * 5 + i) * 64;
      const int s = slot0 + lane;
      async16(Bs + slot0 * 8, Bw + (size_t)(s >> 3) * 4096 + k0 + (s & 7) * 8);
    }
    asm volatile("s_waitcnt vmcnt(0)" ::: "memory");
    __syncthreads();
#pragma unroll
    for (int kk = 0; kk < BK; kk += 32) {
      bf16x8 af = *(const bf16x8*)(As + (w * 16 + r) * BK + kk + kq);
#pragma unroll
      for (int fn = 0; fn < 10; ++fn) {
        bf16x8 bb = *(const bf16x8*)(Bs + (fn * 16 + r) * BK + kk + kq);
        acc[fn] = __builtin_amdgcn_mfma_f32_16x16x32_bf16(af, bb, acc[fn], 0, 0, 0);
      }
    }
    __syncthreads();
  }
  float* o = part + (size_t)kz * B_ROWS * 160;
  const int rr = (lane >> 4) * 4, cc = lane & 15;
#pragma unroll
  for (int fn = 0; fn < 10; ++fn)
#pragma unroll
    for (int tt = 0; tt < 4; ++tt)
      o[(size_t)(m0 + w * 16 + rr + tt) * 160 + fn * 16 + cc] = acc[fn][tt];
}

// ---------------- reduce split-K partials -> dt_lo (bf16) + bc ----------------
__global__ __launch_bounds__(192)
void xdbl_reduce(const float* __restrict__ part, u16* __restrict__ dtlo,
                 float* __restrict__ bc)
{
  const int row = blockIdx.x, t = threadIdx.x;
  __shared__ float cvals[32];
  float v = 0.0f;
  if (t < 160) {
    const float* p = part + (size_t)row * 160 + t;
#pragma unroll
    for (int z = 0; z < 4; ++z) v += p[(size_t)z * B_ROWS * 160];
  }
  if (t < DT_RANK) dtlo[(size_t)row * DT_RANK + t] = f2bf(v);
  if (t >= DT_RANK && t < 160) cvals[t - DT_RANK] = v;
  __syncthreads();
  if (t == 0) {
    float s = 0.0f;
#pragma unroll
    for (int j = 0; j < 16; ++j) s += cvals[j] * cvals[j + 16];
    bc[row] = s;
  }
}

// ---------------- row LayerNorm over (p0 + p1 + h) ----------------
__global__ __launch_bounds__(256)
void ln_kernel(const float* __restrict__ p0, const float* __restrict__ p1,
               const float* __restrict__ hh, const float* __restrict__ gamma,
               const float* __restrict__ beta, float* __restrict__ out)
{
  const int row = blockIdx.x, t = threadIdx.x;
  __shared__ float red[4];
  const float4* x0 = (const float4*)(p0 + (size_t)row * N_HIDDEN);
  const float4* x1 = (const float4*)(p1 + (size_t)row * N_HIDDEN);
  const float4* xh = (const float4*)(hh + (size_t)row * N_HIDDEN);
  float4 a, b;
  {
    float4 u = x0[t], v = x1[t], w = xh[t];
    a.x = u.x + v.x + w.x; a.y = u.y + v.y + w.y; a.z = u.z + v.z + w.z; a.w = u.w + v.w + w.w;
    u = x0[t + 256]; v = x1[t + 256]; w = xh[t + 256];
    b.x = u.x + v.x + w.x; b.y = u.y + v.y + w.y; b.z = u.z + v.z + w.z; b.w = u.w + v.w + w.w;
  }
  float s = ((a.x + a.y) + (a.z + a.w)) + ((b.x + b.y) + (b.z + b.w));
#pragma unroll
  for (int m = 32; m; m >>= 1) s += __shfl_xor(s, m);
  if ((t & 63) == 0) red[t >> 6] = s;
  __syncthreads();
  s = (red[0] + red[1]) + (red[2] + red[3]);
  const float mu = s * (1.0f / N_HIDDEN);
  float dx0 = a.x - mu, dx1 = a.y - mu, dx2 = a.z - mu, dx3 = a.w - mu;
  float dy0 = b.x - mu, dy1 = b.y - mu, dy2 = b.z - mu, dy3 = b.w - mu;
  float q = ((dx0 * dx0 + dx1 * dx1) + (dx2 * dx2 + dx3 * dx3)) +
            ((dy0 * dy0 + dy1 * dy1) + (dy2 * dy2 + dy3 * dy3));
  __syncthreads();
#pragma unroll
  for (int m = 32; m; m >>= 1) q += __shfl_xor(q, m);
  if ((t & 63) == 0) red[t >> 6] = q;
  __syncthreads();
  q = (red[0] + red[1]) + (red[2] + red[3]);
  const float inv = rsqrtf(q * (1.0f / N_HIDDEN) + 1e-5f);
  const float4 ga = ((const float4*)gamma)[t], gb = ((const float4*)gamma)[t + 256];
  const float4 ba = ((const float4*)beta)[t], bbv = ((const float4*)beta)[t + 256];
  float4 o0, o1;
  o0.x = dx0 * inv * ga.x + ba.x;
  o0.y = dx1 * inv * ga.y + ba.y;
  o0.z = dx2 * inv * ga.z + ba.z;
  o0.w = dx3 * inv * ga.w + ba.w;
  o1.x = dy0 * inv * gb.x + bbv.x;
  o1.y = dy1 * inv * gb.y + bbv.y;
  o1.z = dy2 * inv * gb.z + bbv.z;
  o1.w = dy3 * inv * gb.w + bbv.w;
  float4* o4 = (float4*)(out + (size_t)row * N_HIDDEN);
  o4[t] = o0;
  o4[t + 256] = o1;
}

// ---------------- launch ----------------
extern "C" void kernel_launch(void* const* d_in, const int* in_sizes, int n_in,
                              void* d_out, int out_size, void* d_ws, size_t ws_size,
                              hipStream_t stream) {
  const float* x     = (const float*)d_in[0];
  const float* h     = (const float*)d_in[1];
  const float* W_in  = (const float*)d_in[2];
  const float* W_st  = (const float*)d_in[3];
  const float* W_xp  = (const float*)d_in[4];
  const float* W_dt  = (const float*)d_in[5];
  const float* b_dt  = (const float*)d_in[6];
  const float* Dv    = (const float*)d_in[8];
  const float* W_out = (const float*)d_in[9];
  const float* gamma = (const float*)d_in[10];
  const float* beta  = (const float*)d_in[11];
  float* out = (float*)d_out;
  (void)in_sizes; (void)n_in; (void)out_size; (void)ws_size;

  char* ws = (char*)d_ws;
  size_t o = 0;
  auto alloc = [&](size_t bytes) { char* p = ws + o; o += bytes; return p; };
  u16* Acat    = (u16*)alloc((size_t)4096 * 3072 * 2);  // [x | h]   (region reused for y)
  u16* Wcat    = (u16*)alloc((size_t)4096 * 3072 * 2);  // [W_in_lo | W_st]
  u16* Wz_bf   = (u16*)alloc((size_t)4096 * 1024 * 2);
  u16* Wxp_bf  = (u16*)alloc((size_t)160 * 4096 * 2);
  u16* Wdt_bf  = (u16*)alloc((size_t)4096 * 128 * 2);
  u16* Wout_bf = (u16*)alloc((size_t)2048 * 4096 * 2);
  u16* xbr_bf  = (u16*)alloc((size_t)4096 * 4096 * 2);  // reused for p0 (f32)
  u16* sz_bf   = (u16*)alloc((size_t)4096 * 4096 * 2);  // reused for p1 (f32)
  float* part  = (float*)alloc((size_t)4 * 4096 * 160 * 4);
  u16* dtlo_bf = (u16*)alloc((size_t)4096 * 128 * 2);
  float* bc    = (float*)alloc((size_t)4096 * 4);
  // overlays (lifetimes are disjoint):
  u16* y_bf = (u16*)Acat;                  // Acat+Wcat dead by then
  float* p0 = (float*)xbr_bf;              // W_out split-K partials, contiguous
  float* p1 = p0 + (size_t)4096 * 2048;

  // ---- single merged convert launch (8 jobs)
  CvtJobs J;
  J.src[0] = x;                           J.dst[0] = Acat;        J.rl4[0] = 256;  J.dstride[0] = 3072;
  J.src[1] = h;                           J.dst[1] = Acat + 1024; J.rl4[1] = 512;  J.dstride[1] = 3072;
  J.src[2] = W_in;                        J.dst[2] = Wcat;        J.rl4[2] = 256;  J.dstride[2] = 3072;
  J.src[3] = W_st;                        J.dst[3] = Wcat + 1024; J.rl4[3] = 512;  J.dstride[3] = 3072;
  J.src[4] = W_in + (size_t)4096 * 1024;  J.dst[4] = Wz_bf;       J.rl4[4] = 256;  J.dstride[4] = 1024;
  J.src[5] = W_xp;                        J.dst[5] = Wxp_bf;      J.rl4[5] = 1024; J.dstride[5] = 4096;
  J.src[6] = W_dt;                        J.dst[6] = Wdt_bf;      J.rl4[6] = 32;   J.dstride[6] = 128;
  J.src[7] = W_out;                       J.dst[7] = Wout_bf;     J.rl4[7] = 1024; J.dstride[7] = 4096;
  const int rows[8] = {4096, 4096, 4096, 4096, 4096, 160, 4096, 2048};
  J.cum[0] = 0;
  for (int k = 0; k < 8; ++k) J.cum[k + 1] = J.cum[k] + rows[k];
  cvt_all_kernel<<<J.cum[8], 256, 0, stream>>>(J);

  // x_br = silu([x|h] @ [W_in_lo|W_st]^T)   M=4096,N=4096,K=3072  (16x16 grid, 4x8 rect)
  gemm8<4096, 3072, 3072, 3072, 0, 16, 16, 4, 8><<<dim3(16, 16, 1), 512, 131072, stream>>>(
      Acat, Wcat, nullptr, xbr_bf, 0);
  // sz = silu(x @ W_in_hi^T)                M=4096,N=4096,K=1024
  gemm8<4096, 1024, 3072, 1024, 0, 16, 16, 4, 8><<<dim3(16, 16, 1), 512, 131072, stream>>>(
      Acat, Wz_bf, nullptr, sz_bf, 0);
  // x_dbl split-K partials + reduce -> dt_lo, bc
  gemm_xproj<<<dim3(64, 4), 256, 0, stream>>>(xbr_bf, Wxp_bf, part);
  xdbl_reduce<<<4096, 192, 0, stream>>>(part, dtlo_bf, bc);
  // y = x_br*(softplus(dt_pre+b_dt)*bc + D)*silu(z)   M=4096,N=4096,K=128
  gemm_bt<4096, 128, 128, 2><<<dim3(32, 32), 256, 0, stream>>>(
      dtlo_bf, Wdt_bf, nullptr, y_bf, b_dt, bc, Dv, xbr_bf, sz_bf);
  // h_new partials: y @ W_out^T, split-K=2  M=4096,N=2048,K=2x2048  (8x16 grid, 4x4 rect)
  gemm8<2048, 2048, 4096, 4096, 1, 8, 16, 4, 4><<<dim3(8, 16, 2), 512, 131072, stream>>>(
      y_bf, Wout_bf, p0, nullptr, (long long)4096 * 2048);
  // LayerNorm(p0 + p1 + h) -> out
  ln_kernel<<<4096, 256, 0, stream>>>(p0, p1, h, gamma, beta, out);
}